// Round 12
// baseline (367.956 us; speedup 1.0000x reference)
//
#include <hip/hip_runtime.h>
#include <hip/hip_bf16.h>

typedef unsigned short u16;
typedef __attribute__((ext_vector_type(8))) short bf16x8;
typedef __attribute__((ext_vector_type(8))) unsigned short us8;
typedef __attribute__((ext_vector_type(4))) float f32x4;

#define T_Q 32
#define T_K 48
#define NB 64
#define HDIM 1024
#define MASK_FILL -65504.0f
#define LSTM_BLOCKS 64

__device__ __forceinline__ float bf2f(u16 v){
  union { unsigned u; float f; } x; x.u = ((unsigned)v) << 16; return x.f;
}
__device__ __forceinline__ u16 f2bf(float f){
  union { float f; unsigned u; } x; x.f = f;
  return (u16)((x.u + 0x7FFFu + ((x.u >> 16) & 1u)) >> 16);
}
__device__ __forceinline__ float sigm(float x){
  return __builtin_amdgcn_rcpf(1.f + __expf(-x));
}
__device__ __forceinline__ float tanh_f(float x){
  float e = __expf(2.f * x);
  return fmaf(-2.f, __builtin_amdgcn_rcpf(e + 1.f), 1.f);  // graceful at +/-inf
}

// Cross-XCD coherent sync-path ops (sc0 = bypass L0/L1, sc1 = bypass local L2;
// coherence point = Infinity Cache). Used ONLY for the tiny publish/flag path.
// h DATA loads are normal cached loads against write-once rotating buffers (r6).
// r7 lesson: exactly ONE global-polling wave per block.
// r10 lesson: wave-specialized LDS staging regressed (barriers + halved MFMA waves).
// r11 lesson: gemm128 loses to gemm64 at these shapes (2 vs 8 blocks/CU TLP).
__device__ __forceinline__ void st_b32_cc(u16* a, unsigned v){
  asm volatile("global_store_dword %0, %1, off sc0 sc1" :: "v"(a), "v"(v) : "memory");
}
__device__ __forceinline__ void st_flag(int* a, int v){
  asm volatile("global_store_dword %0, %1, off sc0 sc1" :: "v"(a), "v"(v) : "memory");
}
__device__ __forceinline__ int ld_flag(const int* a){
  int r;
  asm volatile("global_load_dword %0, %1, off sc0 sc1\n\ts_waitcnt vmcnt(0)"
               : "=v"(r) : "v"(a) : "memory");
  return r;
}

#define MFMA16(A,B,C) __builtin_amdgcn_mfma_f32_16x16x32_bf16(A,B,C,0,0,0)

// ---------------- prep kernels ----------------

__global__ void conv_f2b(const float* __restrict__ s, u16* __restrict__ d){
  size_t i = ((size_t)blockIdx.x * 256 + threadIdx.x) * 4;
  float4 v = *(const float4*)(s + i);
  ushort4 o; o.x = f2bf(v.x); o.y = f2bf(v.y); o.z = f2bf(v.z); o.w = f2bf(v.w);
  *(ushort4*)(d + i) = o;
}

__global__ void gather_x(const int* __restrict__ tok, const float* __restrict__ emb,
                         u16* __restrict__ x){
  int r = blockIdx.x;                      // r = t*64 + b
  int token = tok[r];
  float4 v = ((const float4*)(emb + (size_t)token * HDIM))[threadIdx.x];
  ushort4 o; o.x = f2bf(v.x); o.y = f2bf(v.y); o.z = f2bf(v.z); o.w = f2bf(v.w);
  ((ushort4*)(x + (size_t)r * HDIM))[threadIdx.x] = o;
}

__global__ void make_keys(const float* __restrict__ a, const float* __restrict__ b,
                          u16* __restrict__ o){
  size_t i = ((size_t)blockIdx.x * 256 + threadIdx.x) * 4;
  float4 va = *(const float4*)(a + i);
  float4 vb = *(const float4*)(b + i);
  ushort4 vo;
  vo.x = f2bf(va.x + vb.x);
  vo.y = f2bf(va.y + vb.y);
  vo.z = f2bf(va.z + vb.z);
  vo.w = f2bf(va.w + vb.w);
  *(ushort4*)(o + i) = vo;
}

__global__ void prep_small(const float* __restrict__ vatt, const float* __restrict__ ns,
                           const float* __restrict__ nb,
                           float* __restrict__ vhat, float* __restrict__ nbias){
  __shared__ float wred[4];
  int t = threadIdx.x, lane = t & 63, w = t >> 6;
  float vv[4]; float s = 0.f;
  #pragma unroll
  for (int j = 0; j < 4; j++){ vv[j] = vatt[t*4 + j]; s += vv[j]*vv[j]; }
  #pragma unroll
  for (int m = 32; m >= 1; m >>= 1) s += __shfl_xor(s, m);
  if (lane == 0) wred[w] = s;
  __syncthreads();
  float tot = wred[0] + wred[1] + wred[2] + wred[3];
  float scale = ns[0] / sqrtf(tot);
  #pragma unroll
  for (int j = 0; j < 4; j++) vhat[t*4 + j] = vv[j] * scale;
  #pragma unroll
  for (int j = 0; j < 4; j++){ int i = t + 256*j; nbias[i] = nb[i]; }
}

__global__ void prep_bsum(const float* __restrict__ bih, const float* __restrict__ bhh,
                          float* __restrict__ bias_sum){
  int i = blockIdx.x * 256 + threadIdx.x;
  bias_sum[i] = bih[i] + bhh[i];
}

// ---------------- generic bf16 GEMM (r6/r9-proven 64x64 tile) ----------------
// C[M][N] = A[M][K] * W[N][K]^T + bias. OB=1 -> bf16 out, OB=0 -> f32 out.

template<int OB>
__global__ __launch_bounds__(256) void gemm_bf16(
  const u16* __restrict__ A, const u16* __restrict__ W,
  const float* __restrict__ bias, void* __restrict__ Cv,
  int M, int N, int K)
{
  __shared__ __align__(16) u16 As[4][66][8];   // [kc][row][8], kc-stride 1056B
  __shared__ __align__(16) u16 Bs[4][66][8];
  const int t = threadIdx.x;
  const int m0 = blockIdx.y * 64, n0 = blockIdx.x * 64;
  const int lane = t & 63, w = t >> 6;
  const int wm = (w >> 1) * 32, wn = (w & 1) * 32;
  const int lr = lane & 15, g = lane >> 4;
  const int lrow = t >> 2, lkc = t & 3;
  f32x4 acc00 = {0,0,0,0}, acc01 = {0,0,0,0}, acc10 = {0,0,0,0}, acc11 = {0,0,0,0};
  const u16* aptr = A + (size_t)(m0 + lrow) * K + lkc * 8;
  const u16* wptr = W + (size_t)(n0 + lrow) * K + lkc * 8;
  for (int k0 = 0; k0 < K; k0 += 32){
    *(bf16x8*)(&As[lkc][lrow][0]) = *(const bf16x8*)(aptr + k0);
    *(bf16x8*)(&Bs[lkc][lrow][0]) = *(const bf16x8*)(wptr + k0);
    __syncthreads();
    bf16x8 a0 = *(const bf16x8*)(&As[g][wm      + lr][0]);
    bf16x8 a1 = *(const bf16x8*)(&As[g][wm + 16 + lr][0]);
    bf16x8 b0 = *(const bf16x8*)(&Bs[g][wn      + lr][0]);
    bf16x8 b1 = *(const bf16x8*)(&Bs[g][wn + 16 + lr][0]);
    acc00 = MFMA16(a0, b0, acc00);
    acc01 = MFMA16(a0, b1, acc01);
    acc10 = MFMA16(a1, b0, acc10);
    acc11 = MFMA16(a1, b1, acc11);
    __syncthreads();
  }
  // C/D layout: col = lane&15, row = (lane>>4)*4 + reg   [m89-verified]
  const int rb = m0 + wm + g * 4;
  const int cb = n0 + wn + lr;
  float bv0 = bias ? bias[cb]      : 0.f;
  float bv1 = bias ? bias[cb + 16] : 0.f;
  #pragma unroll
  for (int r = 0; r < 4; r++){
    float v00 = acc00[r] + bv0, v01 = acc01[r] + bv1;
    float v10 = acc10[r] + bv0, v11 = acc11[r] + bv1;
    if (OB){
      u16* C = (u16*)Cv;
      C[(size_t)(rb + r)      * N + cb]      = f2bf(v00);
      C[(size_t)(rb + r)      * N + cb + 16] = f2bf(v01);
      C[(size_t)(rb + 16 + r) * N + cb]      = f2bf(v10);
      C[(size_t)(rb + 16 + r) * N + cb + 16] = f2bf(v11);
    } else {
      float* C = (float*)Cv;
      C[(size_t)(rb + r)      * N + cb]      = v00;
      C[(size_t)(rb + r)      * N + cb + 16] = v01;
      C[(size_t)(rb + 16 + r) * N + cb]      = v10;
      C[(size_t)(rb + 16 + r) * N + cb + 16] = v11;
    }
  }
}

// ---------------- persistent LSTM (r12: DUAL-CHAIN phase interleave) ----------------
// Batch rows are INDEPENDENT recurrence chains; only columns couple blocks.
// Chain A = rows 0-31, chain B = rows 32-63, both run by every block,
// phase-interleaved: while A's h(t) propagates L3->flags->consumers, the block
// computes B's step t. The publish->detect RT chain + skew (the ~4us/step cost
// that r7/r9/r10 couldn't dent) is filled with real work instead of stalling.
// Primitives unchanged from r6/r9 (all verified): write-once rotating buffers
// per chain, sc0sc1 publish + vmcnt + per-block flag, wave-0-only ballot poll,
// normal cached consumer loads, m89 C/D layout. Tile geometry halved (M=32).

__global__ __launch_bounds__(512, 1) void lstm_persistent(
  const float* __restrict__ Whh, const u16* __restrict__ xp,
  u16* __restrict__ hsA, u16* __restrict__ hsB,
  u16* __restrict__ qbuf, float* __restrict__ out0,
  int* __restrict__ flagsA, int* __restrict__ flagsB)
{
  extern __shared__ char smem[];
  u16*  wlds = (u16*)smem;                    // [4][32][16][32] bf16 (128KB)
  float* gl  = (float*)(smem + 131072);       // [4][32][16] f32 (8KB, reused per phase)

  const int tid = threadIdx.x;
  const int c0 = blockIdx.x * 16;
  const int lane = tid & 63, w = tid >> 6;    // 8 waves
  const int gate = w & 3, msub = w >> 2;      // wave -> (gate, 16-row half of chain)
  const int lr = lane & 15, g = lane >> 4;

  // ---- one-time: Whh slice f32 -> bf16 -> LDS (unchanged, verified) ----
  #pragma unroll
  for (int i = 0; i < 16; i++){
    int e = (i * 512 + tid) * 8;               // element in 64x1024 slice
    int R = e >> 10, k = e & 1023;
    int gg = R >> 4, rr = R & 15, tt = k >> 5, kk = k & 31;
    const float* src = Whh + (size_t)((gg << 10) + c0 + rr) * 1024 + k;
    float4 v0 = *(const float4*)(src);
    float4 v1 = *(const float4*)(src + 4);
    u16* dst = wlds + (((gg * 32 + tt) * 16 + rr) * 32 + kk);
    ushort4 o0, o1;
    o0.x = f2bf(v0.x); o0.y = f2bf(v0.y); o0.z = f2bf(v0.z); o0.w = f2bf(v0.w);
    o1.x = f2bf(v1.x); o1.y = f2bf(v1.y); o1.z = f2bf(v1.z); o1.w = f2bf(v1.w);
    *(ushort4*)dst = o0; *(ushort4*)(dst + 4) = o1;
  }
  __syncthreads();

  // pointwise ownership (threads < 256): 2 cells of one chain-local row
  const int pb2 = tid >> 3;                    // chain-local row 0..31 (tid<256)
  const int pc  = (tid * 2) & 15;              // even col pair base
  float cA0 = 0.f, cA1 = 0.f, cB0 = 0.f, cB1 = 0.f;

  const int arow2 = msub * 16 + lr;            // chain-local A-fragment row
  // chain-h layout: elem(step,row2,k) = step*32768 + (k>>4)*512 + row2*16 + (k&15)
  const int jc = g >> 1;
  const int cc = (g & 1) * 8;

  int step = 0;

  // one chain phase: detect (if step>0) -> MFMA -> gl -> pointwise -> publish
  auto phase = [&](u16* hs, int* fl, const unsigned* xw, float& cs0, float& cs1,
                   int rowoff) __attribute__((always_inline)) {
    f32x4 acc_e = {0,0,0,0}, acc_o = {0,0,0,0};
    if (step > 0){
      if (w == 0){                             // sole global poller (r7 lesson)
        const int* fp = fl + lane * 16;
        for (;;){
          int f = ld_flag(fp);
          if (__ballot(f >= step) == ~0ull) break;
          __builtin_amdgcn_s_sleep(1);
        }
      }
      __syncthreads();                         // h(step-1) published & visible

      const u16* hb = hs + (size_t)(step - 1) * 32768;
      const u16* pa = hb + (size_t)jc * 512 + (size_t)arow2 * 16 + cc;
      bf16x8 a[8];
      #pragma unroll
      for (int p = 0; p < 8; p++) a[p] = *(const bf16x8*)(pa + p * 1024);
      #pragma unroll
      for (int t = 0; t < 32; t++){
        bf16x8 bfr = *(const bf16x8*)(wlds + ((size_t)(gate * 32 + t) * 16 + lr) * 32 + g * 8);
        if (t & 1) acc_o = MFMA16(a[t & 7], bfr, acc_o);
        else       acc_e = MFMA16(a[t & 7], bfr, acc_e);
        if (t < 24) a[t & 7] = *(const bf16x8*)(pa + (t + 8) * 1024);
      }
    }
    // gl exchange. C/D: col=lane&15, row=(lane>>4)*4+reg [m89]
    #pragma unroll
    for (int r = 0; r < 4; r++)
      gl[(gate * 32 + msub * 16 + g * 4 + r) * 16 + lr] = acc_e[r] + acc_o[r];
    __syncthreads();

    u16 hb0 = 0, hb1 = 0; float ho0 = 0.f, ho1 = 0.f;
    if (tid < 256){
      float ig0 = gl[(0 * 32 + pb2) * 16 + pc] + bf2f((u16)(xw[0] & 0xFFFF));
      float fg0 = gl[(1 * 32 + pb2) * 16 + pc] + bf2f((u16)(xw[1] & 0xFFFF));
      float gg0 = gl[(2 * 32 + pb2) * 16 + pc] + bf2f((u16)(xw[2] & 0xFFFF));
      float og0 = gl[(3 * 32 + pb2) * 16 + pc] + bf2f((u16)(xw[3] & 0xFFFF));
      float cn0 = sigm(fg0) * cs0 + sigm(ig0) * tanh_f(gg0);
      cs0 = cn0; ho0 = sigm(og0) * tanh_f(cn0); hb0 = f2bf(ho0);
      float ig1 = gl[(0 * 32 + pb2) * 16 + pc + 1] + bf2f((u16)(xw[0] >> 16));
      float fg1 = gl[(1 * 32 + pb2) * 16 + pc + 1] + bf2f((u16)(xw[1] >> 16));
      float gg1 = gl[(2 * 32 + pb2) * 16 + pc + 1] + bf2f((u16)(xw[2] >> 16));
      float og1 = gl[(3 * 32 + pb2) * 16 + pc + 1] + bf2f((u16)(xw[3] >> 16));
      float cn1 = sigm(fg1) * cs1 + sigm(ig1) * tanh_f(gg1);
      cs1 = cn1; ho1 = sigm(og1) * tanh_f(cn1); hb1 = f2bf(ho1);
    }

    if (step < T_Q - 1){
      if (tid < 256){
        u16* hw = hs + (size_t)step * 32768 + (size_t)blockIdx.x * 512 + pb2 * 16 + pc;
        st_b32_cc(hw, (unsigned)hb0 | ((unsigned)hb1 << 16));
      }
      asm volatile("s_waitcnt vmcnt(0)" ::: "memory");
      __syncthreads();                         // block's h at L3
      if (tid == 0) st_flag(fl + blockIdx.x * 16, step + 1);
    } else {
      __syncthreads();                         // protect gl before next phase
    }

    if (tid < 256){
      int brow = rowoff + pb2;
      ushort2 hh; hh.x = hb0; hh.y = hb1;
      *(ushort2*)(qbuf + ((size_t)brow * T_Q + step) * HDIM + c0 + pc) = hh;
      float2 ho; ho.x = ho0; ho.y = ho1;
      *(float2*)(out0 + ((size_t)(step * NB + brow)) * HDIM + c0 + pc) = ho;
    }
  };

  #pragma unroll 1
  for (step = 0; step < T_Q; step++){
    unsigned xwA[4] = {0,0,0,0}, xwB[4] = {0,0,0,0};
    if (tid < 256){
      const u16* xrA = xp + ((size_t)(step * NB + pb2)) * 4096 + c0 + pc;
      const u16* xrB = xrA + (size_t)32 * 4096;
      #pragma unroll
      for (int j = 0; j < 4; j++){
        xwA[j] = *(const unsigned*)(xrA + j * 1024);
        xwB[j] = *(const unsigned*)(xrB + j * 1024);
      }
    }
    phase(hsA, flagsA, xwA, cA0, cA1, 0);      // A publish -> B phase hides RT
    phase(hsB, flagsB, xwB, cB0, cB1, 32);     // B publish -> next A phase hides RT
  }
}

// ---------------- fused attention: scores -> softmax -> context ----------------
// block per (b,q). wave w handles keys k in [w*12, min(len,w*12+12)). len-bounded.

__global__ __launch_bounds__(256) void attn_fused(
  const float* __restrict__ aq, const u16* __restrict__ ak,
  const float* __restrict__ vhat, const u16* __restrict__ keys,
  const int* __restrict__ lens, float* __restrict__ out1)
{
  int b = blockIdx.x >> 5, q = blockIdx.x & 31;
  int t = threadIdx.x, lane = t & 63, w = t >> 6;
  __shared__ float sc[T_K];
  __shared__ float ps[T_K];
  int len = lens[b];
  float aqr[16], vh[16];
  const float* aqp = aq + (size_t)(b * T_Q + q) * HDIM + lane * 16;
  const float* vp  = vhat + lane * 16;
  #pragma unroll
  for (int j = 0; j < 4; j++){
    float4 v0 = ((const float4*)aqp)[j];
    float4 v1 = ((const float4*)vp)[j];
    aqr[j*4+0] = v0.x; aqr[j*4+1] = v0.y; aqr[j*4+2] = v0.z; aqr[j*4+3] = v0.w;
    vh[j*4+0]  = v1.x; vh[j*4+1]  = v1.y; vh[j*4+2]  = v1.z; vh[j*4+3]  = v1.w;
  }

  int kmax = len - w * 12; if (kmax > 12) kmax = 12;
  for (int kk = 0; kk < kmax; kk++){
    int k = w * 12 + kk;
    const u16* akp = ak + (size_t)(k * NB + b) * HDIM + lane * 16;
    us8 a0 = *(const us8*)(akp);
    us8 a1 = *(const us8*)(akp + 8);
    float p = 0.f;
    #pragma unroll
    for (int j = 0; j < 8; j++){
      p += tanh_f(aqr[j]     + bf2f(a0[j])) * vh[j];
      p += tanh_f(aqr[8 + j] + bf2f(a1[j])) * vh[8 + j];
    }
    #pragma unroll
    for (int m = 32; m >= 1; m >>= 1) p += __shfl_xor(p, m);
    if (lane == 0) sc[k] = p;
  }
  __syncthreads();
  float mx = -3.0e38f;
  for (int k = 0; k < len; k++) mx = fmaxf(mx, sc[k]);
  if (t < len) ps[t] = __expf(sc[t] - mx);
  __syncthreads();
  float den = 0.f;
  for (int k = 0; k < len; k++) den += ps[k];
  float rden = __builtin_amdgcn_rcpf(den);

  float c0 = 0.f, c1 = 0.f, c2 = 0.f, c3 = 0.f;
  for (int k = 0; k < len; k++){
    float pk = ps[k];
    ushort4 kv = *(const ushort4*)(keys + (size_t)(k * NB + b) * HDIM + t * 4);
    c0 += pk * bf2f(kv.x); c1 += pk * bf2f(kv.y);
    c2 += pk * bf2f(kv.z); c3 += pk * bf2f(kv.w);
  }
  size_t o = (size_t)(q * NB + b) * HDIM + t * 4;
  out1[o + 0] = c0 * rden;
  out1[o + 1] = c1 * rden;
  out1[o + 2] = c2 * rden;
  out1[o + 3] = c3 * rden;
}

// ---------------- launch ----------------

extern "C" void kernel_launch(void* const* d_in, const int* in_sizes, int n_in,
                              void* d_out, int out_size, void* d_ws, size_t ws_size,
                              hipStream_t stream)
{
  const float* in1  = (const float*)d_in[0];   // input1
  const float* in0  = (const float*)d_in[1];   // input0
  const int*   lens = (const int*)d_in[2];     // input2
  const int*   toks = (const int*)d_in[3];     // input3
  const float* emb  = (const float*)d_in[4];
  const float* Wih  = (const float*)d_in[5];
  const float* Whh  = (const float*)d_in[6];
  const float* bih  = (const float*)d_in[7];
  const float* bhh  = (const float*)d_in[8];
  const float* Wq   = (const float*)d_in[9];
  const float* Wk   = (const float*)d_in[10];
  const float* vatt = (const float*)d_in[11];
  const float* ns   = (const float*)d_in[12];
  const float* nbb  = (const float*)d_in[13];

  char* p = (char*)d_ws;
  u16* x_bf    = (u16*)p;   p += (size_t)2048 * 1024 * 2;   // 4 MB
  u16* keys_bf = (u16*)p;   p += (size_t)3072 * 1024 * 2;   // 6 MB
  u16* hsA     = (u16*)p;   p += (size_t)32 * 32768 * 2;    // 2 MB rotating h, chain A
  u16* hsB     = (u16*)p;   p += (size_t)32 * 32768 * 2;    // 2 MB rotating h, chain B
  u16* qbuf    = (u16*)p;   p += (size_t)2048 * 1024 * 2;   // 4 MB
  u16* xp      = (u16*)p;   p += (size_t)2048 * 4096 * 2;   // 16 MB (dead after LSTM)
  float* vhat  = (float*)p; p += 1024 * 4;
  float* bsum  = (float*)p; p += 4096 * 4;
  float* nbf   = (float*)p; p += 1024 * 4;
  int* flagsA  = (int*)p;   p += 4096;                      // 64 flags, 64B apart
  int* flagsB  = (int*)p;   p += 4096;
  u16* ak      = (u16*)p;   p += (size_t)3072 * 1024 * 2;   // 6 MB
  u16* Wih_bf  = (u16*)p;   p += (size_t)4096 * 1024 * 2;   // 8 MB
  u16* Wq_bf   = (u16*)p;   p += (size_t)1024 * 1024 * 2;   // 2 MB
  u16* Wk_bf   = (u16*)p;   p += (size_t)1024 * 1024 * 2;   // 2 MB
  float* aq    = (float*)xp;   // 8 MB, aliases xp (xp fully consumed before aq GEMM)

  float* out0 = (float*)d_out;
  float* out1 = out0 + (size_t)T_Q * NB * HDIM;

  hipMemsetAsync(flagsA, 0, 8192, stream);

  conv_f2b<<<4096, 256, 0, stream>>>(Wih, Wih_bf);
  conv_f2b<<<1024, 256, 0, stream>>>(Wq,  Wq_bf);
  conv_f2b<<<1024, 256, 0, stream>>>(Wk,  Wk_bf);
  gather_x<<<2048, 256, 0, stream>>>(toks, emb, x_bf);
  make_keys<<<3072, 256, 0, stream>>>(in1, in0, keys_bf);
  prep_small<<<1, 256, 0, stream>>>(vatt, ns, nbb, vhat, nbf);
  prep_bsum<<<16, 256, 0, stream>>>(bih, bhh, bsum);

  // xp = x * Wih^T + (bih + bhh) : M=2048, N=4096, K=1024 -> bf16
  gemm_bf16<1><<<dim3(64, 32), 256, 0, stream>>>(x_bf, Wih_bf, bsum, xp, 2048, 4096, 1024);
  // ak = keys * Wk^T + norm_bias : M=3072, N=1024, K=1024 -> bf16
  gemm_bf16<1><<<dim3(16, 48), 256, 0, stream>>>(keys_bf, Wk_bf, nbf, ak, 3072, 1024, 1024);

  // all 32 LSTM steps, dual-chain phase-interleaved (136KB dynamic LDS, 1 block/CU)
  lstm_persistent<<<LSTM_BLOCKS, 512, 139264, stream>>>(Whh, xp, hsA, hsB,
                                                        qbuf, out0, flagsA, flagsB);

  // aq = q * Wq^T : M=2048, N=1024, K=1024 -> f32 (writes over xp region, now dead)
  gemm_bf16<0><<<dim3(16, 32), 256, 0, stream>>>(qbuf, Wq_bf, nullptr, aq, 2048, 1024, 1024);

  attn_fused<<<2048, 256, 0, stream>>>(aq, ak, vhat, keys_bf, lens, out1);
}